// Round 5
// baseline (382.161 us; speedup 1.0000x reference)
//
#include <hip/hip_runtime.h>
#include <hip/hip_bf16.h>
#include <cstdint>
#include <cstddef>

#define BATCH 32
#define NPTS  2048
#define NFLAT (BATCH * NPTS)   // 65536
#define MROWS 32               // rows per block in mask/layer1 (8 per wave)

typedef __attribute__((ext_vector_type(8))) short bf16x8;   // 8 bf16 (4 VGPRs)
typedef __attribute__((ext_vector_type(4))) short bf16x4;   // 4 bf16 (2 VGPRs)
typedef __attribute__((ext_vector_type(4))) float f32x4;    // C/D frag

__device__ inline unsigned short f2b(float v) {
    __hip_bfloat16 h = __float2bfloat16(v);
    return __builtin_bit_cast(unsigned short, h);
}

// ---------------- ws layout (bytes) ----------------
// dinv : f32  [65536]                 @ 0
// mask : u32  [65536*64]              @ 262144    (16 MB)
// Yp   : bf16 [b][kt][c][k64] packed  @ 17039360  (<=32 MB)  MFMA-fragment-native
// H    : bf16 [65536*128max] row-maj  @ 50593792  (16 MB)
// Wb   : bf16 [8192+32768]            @ 67371008
#define OFF_DINV 0
#define OFF_MASK 262144
#define OFF_YP   17039360
#define OFF_H    50593792
#define OFF_WB   67371008

// ---------------- convert W2/W3 to bf16 ----------------
__global__ __launch_bounds__(256) void k_cvtW(const float* __restrict__ W2,
                                              const float* __restrict__ W3,
                                              unsigned short* __restrict__ Wb) {
    int i = blockIdx.x * 256 + threadIdx.x;
    if (i < 64 * 128)  Wb[i] = f2b(W2[i]);
    if (i < 128 * 256) Wb[64 * 128 + i] = f2b(W3[i]);
}

// ---------------- adjacency bitmask + dinv (wave-per-row) ----------------
__global__ __launch_bounds__(256) void k_mask(const float* __restrict__ pts,
                                              float* __restrict__ dinv,
                                              uint32_t* __restrict__ mask) {
    const int b = blockIdx.y;
    const int row0 = blockIdx.x * MROWS;
    const int tid = threadIdx.x, lane = tid & 63, wv = tid >> 6;
    __shared__ float px[2112], py[2112];
    const float2* P = (const float2*)(pts + (size_t)b * NPTS * 2);
    for (int j = tid; j < NPTS; j += 256) {
        float2 p = P[j];
        px[j + (j >> 5)] = p.x; py[j + (j >> 5)] = p.y;
    }
    __syncthreads();
    const int base = 33 * lane;
    for (int rr = 0; rr < MROWS / 4; ++rr) {
        const int i = row0 + wv * (MROWS / 4) + rr;
        const float xi = px[i + (i >> 5)], yi = py[i + (i >> 5)];
        uint32_t bits = 0;
        #pragma unroll
        for (int t = 0; t < 32; ++t) {
            float dx = xi - px[base + t], dy = yi - py[base + t];
            bits |= (dx * dx + dy * dy < 1.0f) ? (1u << t) : 0u;
        }
        mask[((size_t)b * NPTS + i) * 64 + lane] = bits;
        int cnt = __popc(bits);
        #pragma unroll
        for (int off = 32; off; off >>= 1) cnt += __shfl_xor(cnt, off);
        if (lane == 0) dinv[b * NPTS + i] = rsqrtf((float)(cnt + 1));
    }
}

// ---------------- layer 1 via (An@p)@W1, wave-per-row ----------------
__global__ __launch_bounds__(256) void k_layer1(const float* __restrict__ pts,
                                                const float* __restrict__ W1,
                                                const float* __restrict__ b1,
                                                const float* __restrict__ dinv,
                                                const uint32_t* __restrict__ mask,
                                                unsigned short* __restrict__ H) {
    const int b = blockIdx.y;
    const int row0 = blockIdx.x * MROWS;
    const int tid = threadIdx.x, lane = tid & 63, wv = tid >> 6;
    __shared__ float u[2112], v[2112];
    const float* dv = dinv + (size_t)b * NPTS;
    const float2* P = (const float2*)(pts + (size_t)b * NPTS * 2);
    for (int j = tid; j < NPTS; j += 256) {
        float d = dv[j]; float2 p = P[j];
        u[j + (j >> 5)] = d * p.x; v[j + (j >> 5)] = d * p.y;
    }
    __syncthreads();
    const float w1x = W1[lane], w1y = W1[64 + lane], bb = b1[lane];
    const int base = 33 * lane;
    for (int rr = 0; rr < MROWS / 4; ++rr) {
        const int i = row0 + wv * (MROWS / 4) + rr;
        const uint32_t wreg = mask[((size_t)b * NPTS + i) * 64 + lane];
        float sx = 0.f, sy = 0.f;
        #pragma unroll
        for (int t = 0; t < 32; ++t) {
            uint32_t m = 0u - ((wreg >> t) & 1u);
            sx += __uint_as_float(__float_as_uint(u[base + t]) & m);
            sy += __uint_as_float(__float_as_uint(v[base + t]) & m);
        }
        #pragma unroll
        for (int off = 32; off; off >>= 1) {
            sx += __shfl_xor(sx, off);
            sy += __shfl_xor(sy, off);
        }
        sx += u[i + (i >> 5)]; sy += v[i + (i >> 5)];   // extra self-loop (diag weight 2)
        const float di = dv[i];
        float val = di * (sx * w1x + sy * w1y) + bb;
        H[((size_t)b * NPTS + i) * 64 + lane] = f2b(fmaxf(val, 0.f));
    }
}

// ---------------- Yp = pack(dinv_i * (H @ W)^T) in MFMA-B-fragment layout ----------------
// Yp[((b*32+kt)*CW + c)*64 + k],  kt = i/64, k = i%64
template<int CW, int KT>
__global__ __launch_bounds__(256, 2) void k_hwT(const unsigned short* __restrict__ H,
                                                const unsigned short* __restrict__ Wg,
                                                const float* __restrict__ dinv,
                                                unsigned short* __restrict__ Yp) {
    constexpr int BI = 256, BC = 128;
    const int i0 = blockIdx.x * BI;
    const int c0 = blockIdx.y * BC;
    const int tid = threadIdx.x, lane = tid & 63, wv = tid >> 6;
    const int l15 = lane & 15, lg = lane >> 4;

    __shared__ unsigned short Wt[BC][KT + 8];
    for (int idx = tid; idx < BC * KT; idx += 256) {
        int c = idx & (BC - 1), k = idx >> 7;
        Wt[c][k] = Wg[(size_t)k * CW + c0 + c];
    }
    __syncthreads();

    const int iw0 = i0 + wv * 64;
    bf16x8 hb[4][KT / 32];
    #pragma unroll
    for (int if_ = 0; if_ < 4; ++if_) {
        const unsigned short* hrow = H + (size_t)(iw0 + if_ * 16 + l15) * KT;
        #pragma unroll
        for (int kq = 0; kq < KT / 32; ++kq)
            hb[if_][kq] = *(const bf16x8*)(hrow + kq * 32 + lg * 8);
    }

    f32x4 acc[8][4];
    #pragma unroll
    for (int cf = 0; cf < 8; ++cf)
        #pragma unroll
        for (int if_ = 0; if_ < 4; ++if_)
            acc[cf][if_] = (f32x4){0.f, 0.f, 0.f, 0.f};

    #pragma unroll
    for (int kq = 0; kq < KT / 32; ++kq)
        #pragma unroll
        for (int cf = 0; cf < 8; ++cf) {
            bf16x8 wa = *(const bf16x8*)&Wt[cf * 16 + l15][kq * 32 + lg * 8];
            #pragma unroll
            for (int if_ = 0; if_ < 4; ++if_)
                acc[cf][if_] = __builtin_amdgcn_mfma_f32_16x16x32_bf16(wa, hb[if_][kq], acc[cf][if_], 0, 0, 0);
        }

    const int bI = i0 >> 11;
    const int ktbase = (i0 & (NPTS - 1)) >> 6;
    float dv[4];
    #pragma unroll
    for (int if_ = 0; if_ < 4; ++if_) dv[if_] = dinv[iw0 + if_ * 16 + l15];
    #pragma unroll
    for (int cf = 0; cf < 8; ++cf)
        #pragma unroll
        for (int if_ = 0; if_ < 4; ++if_) {
            const int ktw = ktbase + wv;
            const int kb = if_ * 16 + l15;
            #pragma unroll
            for (int r = 0; r < 4; ++r) {
                const int cg = c0 + cf * 16 + lg * 4 + r;
                Yp[(((size_t)bI * 32 + ktw) * CW + cg) * 64 + kb] = f2b(dv[if_] * acc[cf][if_][r]);
            }
        }
}

// ---------------- masked GCN GEMM, LDS-free B path + register double-buffer ----------------
// 512 threads, wave grid 2m x 4n; B-frags read from L2-resident fragment-native Yp,
// prefetched one K-tile ahead into registers; A expanded from bitmask via nibble LUT.
template<int BN, bool RELU, bool F32OUT>
__global__ __launch_bounds__(512, 2) void k_gcnR(const uint32_t* __restrict__ mask,
                                                 const float* __restrict__ dinv,
                                                 const unsigned short* __restrict__ Yp,
                                                 const float* __restrict__ bias,
                                                 void* __restrict__ outp) {
    constexpr int BM = 128;
    constexpr int NF = BN / 64;           // per-wave n-frags (2m x 4n wave grid)
    const int lid = blockIdx.x;
    const int g = (lid & 7) * 64 + (lid >> 3);   // bijective XCD swizzle: 4 batches/XCD
    const int b = g >> 4;
    const int row0 = (g & 15) * BM;
    const int tid = threadIdx.x;
    const int lane = tid & 63, wv = tid >> 6;
    const int wm = wv >> 2, wn = wv & 3;
    const int l15 = lane & 15, lg = lane >> 4;

    __shared__ alignas(128) unsigned short LUT4[64];  // 16 entries x 4 bf16 {0,1}
    __shared__ float sdinv[BM];
    if (tid < 16) {
        ushort4 e;
        e.x = (tid & 1) ? 0x3F80 : 0; e.y = (tid & 2) ? 0x3F80 : 0;
        e.z = (tid & 4) ? 0x3F80 : 0; e.w = (tid & 8) ? 0x3F80 : 0;
        *(ushort4*)&LUT4[tid * 4] = e;
    }
    if (tid < BM) sdinv[tid] = dinv[b * NPTS + row0 + tid];
    __syncthreads();

    f32x4 acc[4][NF];
    #pragma unroll
    for (int mf = 0; mf < 4; ++mf)
        #pragma unroll
        for (int nf = 0; nf < NF; ++nf)
            acc[mf][nf] = (f32x4){0.f, 0.f, 0.f, 0.f};

    const int ktd = (row0 >> 6) + wm;     // K-tile containing this wave's diagonal
    const uint32_t* mb = mask + ((size_t)b * NPTS + row0 + wm * 64 + l15) * 64;
    const unsigned short* yb = Yp + ((size_t)b * 32) * BN * 64
                                  + ((size_t)(wn * (BN / 4) + l15)) * 64 + lg * 8;

    auto mload = [&](uint32_t (&M)[8], int kt) {
        #pragma unroll
        for (int mf = 0; mf < 4; ++mf)
            #pragma unroll
            for (int q = 0; q < 2; ++q)
                M[mf * 2 + q] = mb[(size_t)(mf * 16) * 64 + kt * 2 + q];
    };
    auto yload = [&](bf16x8 (&Y)[NF][2], int kt) {
        #pragma unroll
        for (int nf = 0; nf < NF; ++nf)
            #pragma unroll
            for (int kk2 = 0; kk2 < 2; ++kk2)
                Y[nf][kk2] = *(const bf16x8*)(yb + (size_t)kt * BN * 64 + nf * 1024 + kk2 * 32);
    };
    auto body = [&](const uint32_t (&M)[8], const bf16x8 (&Y)[NF][2], int kt) {
        #pragma unroll
        for (int kk2 = 0; kk2 < 2; ++kk2) {
            bf16x8 af[4];
            #pragma unroll
            for (int mf = 0; mf < 4; ++mf) {
                uint32_t by = (M[mf * 2 + kk2] >> (lg * 8)) & 0xffu;
                bf16x4 lo = *(const bf16x4*)&LUT4[(by & 15u) * 4];
                bf16x4 hi = *(const bf16x4*)&LUT4[(by >> 4) * 4];
                af[mf] = __builtin_shufflevector(lo, hi, 0, 1, 2, 3, 4, 5, 6, 7);
            }
            if (kt == ktd) {   // diag weight 2 (self-loop doubling)
                #pragma unroll
                for (int mf = 0; mf < 4; ++mf) {
                    int e = mf * 16 + l15 - kk2 * 32 - lg * 8;
                    #pragma unroll
                    for (int e2 = 0; e2 < 8; ++e2)
                        if (e2 == e) af[mf][e2] = (short)0x4000;
                }
            }
            #pragma unroll
            for (int nf = 0; nf < NF; ++nf)
                #pragma unroll
                for (int mf = 0; mf < 4; ++mf)
                    acc[mf][nf] = __builtin_amdgcn_mfma_f32_16x16x32_bf16(af[mf], Y[nf][kk2], acc[mf][nf], 0, 0, 0);
        }
    };

    uint32_t m0[8], m1[8];
    bf16x8 y0[NF][2], y1[NF][2];
    mload(m0, 0); yload(y0, 0);
    for (int kt = 0; kt < NPTS / 64; kt += 2) {
        mload(m1, kt + 1); yload(y1, kt + 1);   // issue next-tile loads before consuming y0
        body(m0, y0, kt);
        if (kt + 2 < NPTS / 64) { mload(m0, kt + 2); yload(y0, kt + 2); }
        body(m1, y1, kt + 1);
    }

    // ---- epilogue ----
    #pragma unroll
    for (int mf = 0; mf < 4; ++mf) {
        #pragma unroll
        for (int nf = 0; nf < NF; ++nf) {
            const int gc = wn * (BN / 4) + nf * 16 + l15;
            const float bb = bias[gc];
            #pragma unroll
            for (int r = 0; r < 4; ++r) {
                const int lr = wm * 64 + mf * 16 + lg * 4 + r;
                float vv = sdinv[lr] * acc[mf][nf][r] + bb;
                if (RELU) vv = fmaxf(vv, 0.f);
                size_t o = ((size_t)(b * NPTS + row0 + lr)) * BN + gc;
                if (F32OUT) ((float*)outp)[o] = vv;
                else        ((unsigned short*)outp)[o] = f2b(vv);
            }
        }
    }
}

extern "C" void kernel_launch(void* const* d_in, const int* in_sizes, int n_in,
                              void* d_out, int out_size, void* d_ws, size_t ws_size,
                              hipStream_t stream) {
    const float* pts = (const float*)d_in[0];
    const float* W1  = (const float*)d_in[1];
    const float* b1  = (const float*)d_in[2];
    const float* W2  = (const float*)d_in[3];
    const float* b2  = (const float*)d_in[4];
    const float* W3  = (const float*)d_in[5];
    const float* b3  = (const float*)d_in[6];

    char* ws = (char*)d_ws;
    float*          dinv = (float*)(ws + OFF_DINV);
    uint32_t*       mask = (uint32_t*)(ws + OFF_MASK);
    unsigned short* Yp   = (unsigned short*)(ws + OFF_YP);
    unsigned short* H    = (unsigned short*)(ws + OFF_H);
    unsigned short* Wb   = (unsigned short*)(ws + OFF_WB);
    float* out = (float*)d_out;

    k_cvtW<<<dim3(128), dim3(256), 0, stream>>>(W2, W3, Wb);
    k_mask<<<dim3(NPTS / MROWS, BATCH), dim3(256), 0, stream>>>(pts, dinv, mask);
    k_layer1<<<dim3(NPTS / MROWS, BATCH), dim3(256), 0, stream>>>(pts, W1, b1, dinv, mask, H);
    k_hwT<128, 64><<<dim3(NFLAT / 256, 1), dim3(256), 0, stream>>>(H, Wb, dinv, Yp);
    k_gcnR<128, true, false><<<dim3(512), dim3(512), 0, stream>>>(mask, dinv, Yp, b2, H);
    k_hwT<256, 128><<<dim3(NFLAT / 256, 2), dim3(256), 0, stream>>>(H, Wb + 64 * 128, dinv, Yp);
    k_gcnR<256, false, true><<<dim3(512), dim3(512), 0, stream>>>(mask, dinv, Yp, b3, out);
}

// Round 6
// 274.120 us; speedup vs baseline: 1.3941x; 1.3941x over previous
//
#include <hip/hip_runtime.h>
#include <hip/hip_bf16.h>
#include <cstdint>
#include <cstddef>

#define BATCH 32
#define NPTS  2048
#define NFLAT (BATCH * NPTS)   // 65536
#define MROWS 32               // rows per block in mask/layer1 (8 per wave)

typedef __attribute__((ext_vector_type(8))) short bf16x8;   // 8 bf16 (4 VGPRs)
typedef __attribute__((ext_vector_type(4))) short bf16x4;   // 4 bf16 (2 VGPRs)
typedef __attribute__((ext_vector_type(4))) float f32x4;    // C/D frag

__device__ inline unsigned short f2b(float v) {
    __hip_bfloat16 h = __float2bfloat16(v);
    return __builtin_bit_cast(unsigned short, h);
}

__device__ inline void gl_lds16(const void* g, void* l) {
    __builtin_amdgcn_global_load_lds(
        (const __attribute__((address_space(1))) unsigned int*)g,
        (__attribute__((address_space(3))) unsigned int*)l, 16, 0, 0);
}

// ---------------- ws layout (bytes) ----------------
// dinv : f32  [65536]          @ 0
// mask : u32  [65536*64]       @ 262144    (16 MB)
// Yt   : bf16 [256][65536]     @ 17039360  (32 MB)  transposed dinv-scaled H@W
// H    : bf16 [65536*128max]   @ 50593792  (16 MB)
// Wb   : bf16 [8192+32768]     @ 67371008
#define OFF_DINV 0
#define OFF_MASK 262144
#define OFF_YT   17039360
#define OFF_H    50593792
#define OFF_WB   67371008

// ---------------- convert W2/W3 to bf16 ----------------
__global__ __launch_bounds__(256) void k_cvtW(const float* __restrict__ W2,
                                              const float* __restrict__ W3,
                                              unsigned short* __restrict__ Wb) {
    int i = blockIdx.x * 256 + threadIdx.x;
    if (i < 64 * 128)  Wb[i] = f2b(W2[i]);
    if (i < 128 * 256) Wb[64 * 128 + i] = f2b(W3[i]);
}

// ---------------- adjacency bitmask + dinv (wave-per-row) ----------------
__global__ __launch_bounds__(256) void k_mask(const float* __restrict__ pts,
                                              float* __restrict__ dinv,
                                              uint32_t* __restrict__ mask) {
    const int b = blockIdx.y;
    const int row0 = blockIdx.x * MROWS;
    const int tid = threadIdx.x, lane = tid & 63, wv = tid >> 6;
    __shared__ float px[2112], py[2112];
    const float2* P = (const float2*)(pts + (size_t)b * NPTS * 2);
    for (int j = tid; j < NPTS; j += 256) {
        float2 p = P[j];
        px[j + (j >> 5)] = p.x; py[j + (j >> 5)] = p.y;
    }
    __syncthreads();
    const int base = 33 * lane;
    for (int rr = 0; rr < MROWS / 4; ++rr) {
        const int i = row0 + wv * (MROWS / 4) + rr;
        const float xi = px[i + (i >> 5)], yi = py[i + (i >> 5)];
        uint32_t bits = 0;
        #pragma unroll
        for (int t = 0; t < 32; ++t) {
            float dx = xi - px[base + t], dy = yi - py[base + t];
            bits |= (dx * dx + dy * dy < 1.0f) ? (1u << t) : 0u;
        }
        mask[((size_t)b * NPTS + i) * 64 + lane] = bits;
        int cnt = __popc(bits);
        #pragma unroll
        for (int off = 32; off; off >>= 1) cnt += __shfl_xor(cnt, off);
        if (lane == 0) dinv[b * NPTS + i] = rsqrtf((float)(cnt + 1));
    }
}

// ---------------- layer 1 via (An@p)@W1, wave-per-row ----------------
__global__ __launch_bounds__(256) void k_layer1(const float* __restrict__ pts,
                                                const float* __restrict__ W1,
                                                const float* __restrict__ b1,
                                                const float* __restrict__ dinv,
                                                const uint32_t* __restrict__ mask,
                                                unsigned short* __restrict__ H) {
    const int b = blockIdx.y;
    const int row0 = blockIdx.x * MROWS;
    const int tid = threadIdx.x, lane = tid & 63, wv = tid >> 6;
    __shared__ float u[2112], v[2112];
    const float* dv = dinv + (size_t)b * NPTS;
    const float2* P = (const float2*)(pts + (size_t)b * NPTS * 2);
    for (int j = tid; j < NPTS; j += 256) {
        float d = dv[j]; float2 p = P[j];
        u[j + (j >> 5)] = d * p.x; v[j + (j >> 5)] = d * p.y;
    }
    __syncthreads();
    const float w1x = W1[lane], w1y = W1[64 + lane], bb = b1[lane];
    const int base = 33 * lane;
    for (int rr = 0; rr < MROWS / 4; ++rr) {
        const int i = row0 + wv * (MROWS / 4) + rr;
        const uint32_t wreg = mask[((size_t)b * NPTS + i) * 64 + lane];
        float sx = 0.f, sy = 0.f;
        #pragma unroll
        for (int t = 0; t < 32; ++t) {
            uint32_t m = 0u - ((wreg >> t) & 1u);
            sx += __uint_as_float(__float_as_uint(u[base + t]) & m);
            sy += __uint_as_float(__float_as_uint(v[base + t]) & m);
        }
        #pragma unroll
        for (int off = 32; off; off >>= 1) {
            sx += __shfl_xor(sx, off);
            sy += __shfl_xor(sy, off);
        }
        sx += u[i + (i >> 5)]; sy += v[i + (i >> 5)];   // extra self-loop (diag weight 2)
        const float di = dv[i];
        float val = di * (sx * w1x + sy * w1y) + bb;
        H[((size_t)b * NPTS + i) * 64 + lane] = f2b(fmaxf(val, 0.f));
    }
}

// ---------------- Yt = dinv_i * (H @ W)^T   (computed as W^T @ H^T) ----------------
template<int CW, int KT>
__global__ __launch_bounds__(256, 2) void k_hwT(const unsigned short* __restrict__ H,
                                                const unsigned short* __restrict__ Wg,
                                                const float* __restrict__ dinv,
                                                unsigned short* __restrict__ Yt) {
    constexpr int BI = 256, BC = 128;
    const int i0 = blockIdx.x * BI;
    const int c0 = blockIdx.y * BC;
    const int tid = threadIdx.x, lane = tid & 63, wv = tid >> 6;
    const int l15 = lane & 15, lg = lane >> 4;

    __shared__ unsigned short Wt[BC][KT + 8];
    for (int idx = tid; idx < BC * KT; idx += 256) {
        int c = idx & (BC - 1), k = idx >> 7;
        Wt[c][k] = Wg[(size_t)k * CW + c0 + c];
    }
    __syncthreads();

    const int iw0 = i0 + wv * 64;
    bf16x8 hb[4][KT / 32];
    #pragma unroll
    for (int if_ = 0; if_ < 4; ++if_) {
        const unsigned short* hrow = H + (size_t)(iw0 + if_ * 16 + l15) * KT;
        #pragma unroll
        for (int kq = 0; kq < KT / 32; ++kq)
            hb[if_][kq] = *(const bf16x8*)(hrow + kq * 32 + lg * 8);
    }

    f32x4 acc[8][4];
    #pragma unroll
    for (int cf = 0; cf < 8; ++cf)
        #pragma unroll
        for (int if_ = 0; if_ < 4; ++if_)
            acc[cf][if_] = (f32x4){0.f, 0.f, 0.f, 0.f};

    #pragma unroll
    for (int kq = 0; kq < KT / 32; ++kq)
        #pragma unroll
        for (int cf = 0; cf < 8; ++cf) {
            bf16x8 wa = *(const bf16x8*)&Wt[cf * 16 + l15][kq * 32 + lg * 8];
            #pragma unroll
            for (int if_ = 0; if_ < 4; ++if_)
                acc[cf][if_] = __builtin_amdgcn_mfma_f32_16x16x32_bf16(wa, hb[if_][kq], acc[cf][if_], 0, 0, 0);
        }

    float dv[4];
    #pragma unroll
    for (int if_ = 0; if_ < 4; ++if_) dv[if_] = dinv[iw0 + if_ * 16 + l15];
    #pragma unroll
    for (int cf = 0; cf < 8; ++cf)
        #pragma unroll
        for (int if_ = 0; if_ < 4; ++if_) {
            const int ig = iw0 + if_ * 16 + l15;
            #pragma unroll
            for (int r = 0; r < 4; ++r) {
                const int cg = c0 + cf * 16 + lg * 4 + r;
                Yt[(size_t)cg * NFLAT + ig] = f2b(dv[if_] * acc[cf][if_][r]);
            }
        }
}

// ---------------- masked GCN GEMM, double-buffered LDS w/ stage-ahead ----------------
// T3 minimum-2-phase: per K-tile, issue global_load_lds for tile kt+1 into buf^1,
// compute tile kt from buf, then ONE __syncthreads (implicit vmcnt(0) publishes all
// waves' stages). Masks global->regs; A expanded via 128B nibble-LUT (conflict-free).
template<int BN, bool RELU, bool F32OUT>
__global__ __launch_bounds__(256, 2) void k_gcnP(const uint32_t* __restrict__ mask,
                                                 const float* __restrict__ dinv,
                                                 const unsigned short* __restrict__ Yt,
                                                 const float* __restrict__ bias,
                                                 void* __restrict__ outp) {
    constexpr int BM = 128;
    constexpr int NF = BN / 32;           // per-wave n-frags (2x2 wave grid)
    const int lid = blockIdx.x;
    const int g = (lid & 7) * 64 + (lid >> 3);   // bijective XCD swizzle: 4 batches/XCD
    const int b = g >> 4;
    const int row0 = (g & 15) * BM;
    const int tid = threadIdx.x;
    const int lane = tid & 63, wv = tid >> 6;
    const int wm = wv >> 1, wn = wv & 1;
    const int l15 = lane & 15, lg = lane >> 4;

    __shared__ alignas(16) unsigned short Ys[2][BN * 64];  // double-buffered swizzled tiles
    __shared__ alignas(128) unsigned short LUT4[64];       // 16 entries x 4 bf16 {0,1}
    __shared__ float sdinv[BM];
    if (tid < 16) {
        ushort4 e;
        e.x = (tid & 1) ? 0x3F80 : 0; e.y = (tid & 2) ? 0x3F80 : 0;
        e.z = (tid & 4) ? 0x3F80 : 0; e.w = (tid & 8) ? 0x3F80 : 0;
        *(ushort4*)&LUT4[tid * 4] = e;
    }
    if (tid < BM) sdinv[tid] = dinv[b * NPTS + row0 + tid];

    f32x4 acc[4][NF];
    #pragma unroll
    for (int mf = 0; mf < 4; ++mf)
        #pragma unroll
        for (int nf = 0; nf < NF; ++nf)
            acc[mf][nf] = (f32x4){0.f, 0.f, 0.f, 0.f};

    const int ktd = (row0 >> 6) + wm;     // K-tile containing this wave's diagonal
    const int cst = lane >> 3;            // staging sub-row
    const int sst = lane & 7;             // staging stored slot
    const uint32_t* mb = mask + ((size_t)b * NPTS + row0 + wm * 64 + l15) * 64;

    auto stage = [&](int buf, int kt) {
        #pragma unroll
        for (int q = 0; q < BN / 32; ++q) {
            int j = wv * (BN / 32) + q;
            int c = j * 8 + cst;
            int slot = sst ^ (c & 7);
            const unsigned short* gsrc = Yt + (size_t)c * NFLAT + b * NPTS + kt * 64 + slot * 8;
            gl_lds16(gsrc, (char*)&Ys[buf][0] + j * 1024);
        }
    };
    auto mload = [&](uint32_t (&M)[8], int kt) {
        #pragma unroll
        for (int mf = 0; mf < 4; ++mf)
            #pragma unroll
            for (int q = 0; q < 2; ++q)
                M[mf * 2 + q] = mb[(size_t)(mf * 16) * 64 + kt * 2 + q];
    };
    auto body = [&](const uint32_t (&M)[8], int buf, int kt) {
        const char* ybase = (const char*)&Ys[buf][0];
        #pragma unroll
        for (int kk2 = 0; kk2 < 2; ++kk2) {
            bf16x8 af[4];
            #pragma unroll
            for (int mf = 0; mf < 4; ++mf) {
                uint32_t by = (M[mf * 2 + kk2] >> (lg * 8)) & 0xffu;
                bf16x4 lo = *(const bf16x4*)&LUT4[(by & 15u) * 4];
                bf16x4 hi = *(const bf16x4*)&LUT4[(by >> 4) * 4];
                af[mf] = __builtin_shufflevector(lo, hi, 0, 1, 2, 3, 4, 5, 6, 7);
            }
            if (kt == ktd) {   // diag weight 2 (self-loop doubling)
                #pragma unroll
                for (int mf = 0; mf < 4; ++mf) {
                    int e = mf * 16 + l15 - kk2 * 32 - lg * 8;
                    #pragma unroll
                    for (int e2 = 0; e2 < 8; ++e2)
                        if (e2 == e) af[mf][e2] = (short)0x4000;
                }
            }
            __builtin_amdgcn_s_setprio(1);
            #pragma unroll
            for (int nf = 0; nf < NF; ++nf) {
                int c = wn * (BN / 2) + nf * 16 + l15;
                int slot = ((kk2 << 2) + lg) ^ (c & 7);
                bf16x8 bf = *(const bf16x8*)(ybase + c * 128 + slot * 16);
                #pragma unroll
                for (int mf = 0; mf < 4; ++mf)
                    acc[mf][nf] = __builtin_amdgcn_mfma_f32_16x16x32_bf16(af[mf], bf, acc[mf][nf], 0, 0, 0);
            }
            __builtin_amdgcn_s_setprio(0);
        }
    };

    uint32_t mA[8], mB[8];
    stage(0, 0); mload(mA, 0);
    __syncthreads();                       // drains prologue stage, publishes LUT/sdinv

    for (int kt = 0; kt < NPTS / 64; kt += 2) {
        stage(1, kt + 1); mload(mB, kt + 1);    // issue next tile before computing current
        body(mA, 0, kt);
        __syncthreads();                        // implicit vmcnt(0): stage(kt+1) published
        if (kt + 2 < NPTS / 64) { stage(0, kt + 2); mload(mA, kt + 2); }
        body(mB, 1, kt + 1);
        __syncthreads();
    }

    // ---- epilogue ----
    #pragma unroll
    for (int mf = 0; mf < 4; ++mf) {
        #pragma unroll
        for (int nf = 0; nf < NF; ++nf) {
            const int gc = wn * (BN / 2) + nf * 16 + l15;
            const float bb = bias[gc];
            #pragma unroll
            for (int r = 0; r < 4; ++r) {
                const int lr = wm * 64 + mf * 16 + lg * 4 + r;
                float vv = sdinv[lr] * acc[mf][nf][r] + bb;
                if (RELU) vv = fmaxf(vv, 0.f);
                size_t o = ((size_t)(b * NPTS + row0 + lr)) * BN + gc;
                if (F32OUT) ((float*)outp)[o] = vv;
                else        ((unsigned short*)outp)[o] = f2b(vv);
            }
        }
    }
}

extern "C" void kernel_launch(void* const* d_in, const int* in_sizes, int n_in,
                              void* d_out, int out_size, void* d_ws, size_t ws_size,
                              hipStream_t stream) {
    const float* pts = (const float*)d_in[0];
    const float* W1  = (const float*)d_in[1];
    const float* b1  = (const float*)d_in[2];
    const float* W2  = (const float*)d_in[3];
    const float* b2  = (const float*)d_in[4];
    const float* W3  = (const float*)d_in[5];
    const float* b3  = (const float*)d_in[6];

    char* ws = (char*)d_ws;
    float*          dinv = (float*)(ws + OFF_DINV);
    uint32_t*       mask = (uint32_t*)(ws + OFF_MASK);
    unsigned short* Yt   = (unsigned short*)(ws + OFF_YT);
    unsigned short* H    = (unsigned short*)(ws + OFF_H);
    unsigned short* Wb   = (unsigned short*)(ws + OFF_WB);
    float* out = (float*)d_out;

    k_cvtW<<<dim3(128), dim3(256), 0, stream>>>(W2, W3, Wb);
    k_mask<<<dim3(NPTS / MROWS, BATCH), dim3(256), 0, stream>>>(pts, dinv, mask);
    k_layer1<<<dim3(NPTS / MROWS, BATCH), dim3(256), 0, stream>>>(pts, W1, b1, dinv, mask, H);
    k_hwT<128, 64><<<dim3(NFLAT / 256, 1), dim3(256), 0, stream>>>(H, Wb, dinv, Yt);
    k_gcnP<128, true, false><<<dim3(512), dim3(256), 0, stream>>>(mask, dinv, Yt, b2, H);
    k_hwT<256, 128><<<dim3(NFLAT / 256, 2), dim3(256), 0, stream>>>(H, Wb + 64 * 128, dinv, Yt);
    k_gcnP<256, false, true><<<dim3(512), dim3(256), 0, stream>>>(mask, dinv, Yt, b3, out);
}

// Round 7
// 233.107 us; speedup vs baseline: 1.6394x; 1.1759x over previous
//
#include <hip/hip_runtime.h>
#include <hip/hip_bf16.h>
#include <cstdint>
#include <cstddef>

#define BATCH 32
#define NPTS  2048
#define NFLAT (BATCH * NPTS)   // 65536
#define MROWS 32               // rows per block in mask/layer1 (8 per wave)

typedef __attribute__((ext_vector_type(8))) short bf16x8;   // 8 bf16 (4 VGPRs)
typedef __attribute__((ext_vector_type(4))) short bf16x4;   // 4 bf16 (2 VGPRs)
typedef __attribute__((ext_vector_type(4))) float f32x4;    // C/D frag

__device__ inline unsigned short f2b(float v) {
    __hip_bfloat16 h = __float2bfloat16(v);
    return __builtin_bit_cast(unsigned short, h);
}

__device__ inline void gl_lds16(const void* g, void* l) {
    __builtin_amdgcn_global_load_lds(
        (const __attribute__((address_space(1))) unsigned int*)g,
        (__attribute__((address_space(3))) unsigned int*)l, 16, 0, 0);
}

// ---------------- ws layout (bytes) ----------------
// dinv  : f32  [65536]          @ 0
// maskT : u32  [b][64][2048]    @ 262144    (16 MB)  TRANSPOSED: word-plane major
// Yt    : bf16 [256][65536]     @ 17039360  (32 MB)  transposed dinv-scaled H@W
// H     : bf16 [65536*128max]   @ 50593792  (16 MB)
// Wb    : bf16 [8192+32768]     @ 67371008
#define OFF_DINV 0
#define OFF_MASK 262144
#define OFF_YT   17039360
#define OFF_H    50593792
#define OFF_WB   67371008

// ---------------- convert W2/W3 to bf16 ----------------
__global__ __launch_bounds__(256) void k_cvtW(const float* __restrict__ W2,
                                              const float* __restrict__ W3,
                                              unsigned short* __restrict__ Wb) {
    int i = blockIdx.x * 256 + threadIdx.x;
    if (i < 64 * 128)  Wb[i] = f2b(W2[i]);
    if (i < 128 * 256) Wb[64 * 128 + i] = f2b(W3[i]);
}

// ---------------- adjacency bitmask (transposed layout) + dinv ----------------
// Lane l computes word l of its row; LDS transpose so global writes are
// 128B-contiguous per word-plane: maskT[(b*64+w)*2048 + i].
__global__ __launch_bounds__(256) void k_mask(const float* __restrict__ pts,
                                              float* __restrict__ dinv,
                                              uint32_t* __restrict__ maskT) {
    const int b = blockIdx.y;
    const int row0 = blockIdx.x * MROWS;
    const int tid = threadIdx.x, lane = tid & 63, wv = tid >> 6;
    __shared__ float px[2112], py[2112];
    __shared__ uint32_t tb[64][MROWS + 1];
    const float2* P = (const float2*)(pts + (size_t)b * NPTS * 2);
    for (int j = tid; j < NPTS; j += 256) {
        float2 p = P[j];
        px[j + (j >> 5)] = p.x; py[j + (j >> 5)] = p.y;
    }
    __syncthreads();
    const int base = 33 * lane;
    for (int rr = 0; rr < MROWS / 4; ++rr) {
        const int il = wv * (MROWS / 4) + rr;
        const int i = row0 + il;
        const float xi = px[i + (i >> 5)], yi = py[i + (i >> 5)];
        uint32_t bits = 0;
        #pragma unroll
        for (int t = 0; t < 32; ++t) {
            float dx = xi - px[base + t], dy = yi - py[base + t];
            bits |= (dx * dx + dy * dy < 1.0f) ? (1u << t) : 0u;
        }
        tb[lane][il] = bits;
        int cnt = __popc(bits);
        #pragma unroll
        for (int off = 32; off; off >>= 1) cnt += __shfl_xor(cnt, off);
        if (lane == 0) dinv[b * NPTS + i] = rsqrtf((float)(cnt + 1));
    }
    __syncthreads();
    // transposed write: thread t -> plane w = t>>2, cols (t&3)*8 .. +8
    const int w = tid >> 2, il0 = (tid & 3) * 8;
    uint32_t* dst = maskT + ((size_t)b * 64 + w) * NPTS + row0 + il0;
    #pragma unroll
    for (int e = 0; e < 8; ++e) dst[e] = tb[w][il0 + e];
}

// ---------------- layer 1 via (An@p)@W1, wave-per-row ----------------
__global__ __launch_bounds__(256) void k_layer1(const float* __restrict__ pts,
                                                const float* __restrict__ W1,
                                                const float* __restrict__ b1,
                                                const float* __restrict__ dinv,
                                                const uint32_t* __restrict__ maskT,
                                                unsigned short* __restrict__ H) {
    const int b = blockIdx.y;
    const int row0 = blockIdx.x * MROWS;
    const int tid = threadIdx.x, lane = tid & 63, wv = tid >> 6;
    __shared__ float u[2112], v[2112];
    const float* dv = dinv + (size_t)b * NPTS;
    const float2* P = (const float2*)(pts + (size_t)b * NPTS * 2);
    for (int j = tid; j < NPTS; j += 256) {
        float d = dv[j]; float2 p = P[j];
        u[j + (j >> 5)] = d * p.x; v[j + (j >> 5)] = d * p.y;
    }
    __syncthreads();
    const float w1x = W1[lane], w1y = W1[64 + lane], bb = b1[lane];
    const int base = 33 * lane;
    const uint32_t* mplane = maskT + ((size_t)b * 64 + lane) * NPTS;  // lane's word-plane
    for (int rr = 0; rr < MROWS / 4; ++rr) {
        const int i = row0 + wv * (MROWS / 4) + rr;
        const uint32_t wreg = mplane[i];
        float sx = 0.f, sy = 0.f;
        #pragma unroll
        for (int t = 0; t < 32; ++t) {
            uint32_t m = 0u - ((wreg >> t) & 1u);
            sx += __uint_as_float(__float_as_uint(u[base + t]) & m);
            sy += __uint_as_float(__float_as_uint(v[base + t]) & m);
        }
        #pragma unroll
        for (int off = 32; off; off >>= 1) {
            sx += __shfl_xor(sx, off);
            sy += __shfl_xor(sy, off);
        }
        sx += u[i + (i >> 5)]; sy += v[i + (i >> 5)];   // extra self-loop (diag weight 2)
        const float di = dv[i];
        float val = di * (sx * w1x + sy * w1y) + bb;
        H[((size_t)b * NPTS + i) * 64 + lane] = f2b(fmaxf(val, 0.f));
    }
}

// ---------------- Yt = dinv_i * (H @ W)^T   (computed as W^T @ H^T) ----------------
template<int CW, int KT>
__global__ __launch_bounds__(256, 2) void k_hwT(const unsigned short* __restrict__ H,
                                                const unsigned short* __restrict__ Wg,
                                                const float* __restrict__ dinv,
                                                unsigned short* __restrict__ Yt) {
    constexpr int BI = 256, BC = 128;
    const int i0 = blockIdx.x * BI;
    const int c0 = blockIdx.y * BC;
    const int tid = threadIdx.x, lane = tid & 63, wv = tid >> 6;
    const int l15 = lane & 15, lg = lane >> 4;

    __shared__ unsigned short Wt[BC][KT + 8];
    for (int idx = tid; idx < BC * KT; idx += 256) {
        int c = idx & (BC - 1), k = idx >> 7;
        Wt[c][k] = Wg[(size_t)k * CW + c0 + c];
    }
    __syncthreads();

    const int iw0 = i0 + wv * 64;
    bf16x8 hb[4][KT / 32];
    #pragma unroll
    for (int if_ = 0; if_ < 4; ++if_) {
        const unsigned short* hrow = H + (size_t)(iw0 + if_ * 16 + l15) * KT;
        #pragma unroll
        for (int kq = 0; kq < KT / 32; ++kq)
            hb[if_][kq] = *(const bf16x8*)(hrow + kq * 32 + lg * 8);
    }

    f32x4 acc[8][4];
    #pragma unroll
    for (int cf = 0; cf < 8; ++cf)
        #pragma unroll
        for (int if_ = 0; if_ < 4; ++if_)
            acc[cf][if_] = (f32x4){0.f, 0.f, 0.f, 0.f};

    #pragma unroll
    for (int kq = 0; kq < KT / 32; ++kq)
        #pragma unroll
        for (int cf = 0; cf < 8; ++cf) {
            bf16x8 wa = *(const bf16x8*)&Wt[cf * 16 + l15][kq * 32 + lg * 8];
            #pragma unroll
            for (int if_ = 0; if_ < 4; ++if_)
                acc[cf][if_] = __builtin_amdgcn_mfma_f32_16x16x32_bf16(wa, hb[if_][kq], acc[cf][if_], 0, 0, 0);
        }

    float dv[4];
    #pragma unroll
    for (int if_ = 0; if_ < 4; ++if_) dv[if_] = dinv[iw0 + if_ * 16 + l15];
    #pragma unroll
    for (int cf = 0; cf < 8; ++cf)
        #pragma unroll
        for (int if_ = 0; if_ < 4; ++if_) {
            const int ig = iw0 + if_ * 16 + l15;
            #pragma unroll
            for (int r = 0; r < 4; ++r) {
                const int cg = c0 + cf * 16 + lg * 4 + r;
                Yt[(size_t)cg * NFLAT + ig] = f2b(dv[if_] * acc[cf][if_][r]);
            }
        }
}

// ---------------- masked GCN GEMM, double-buffered LDS w/ stage-ahead ----------------
// Masks from TRANSPOSED maskT: each load = one fully-used 64B line, registers +
// 1-tile prefetch. Ys double-buffered via global_load_lds; one barrier per K-tile.
template<int BN, bool RELU, bool F32OUT>
__global__ __launch_bounds__(256, 2) void k_gcnP(const uint32_t* __restrict__ maskT,
                                                 const float* __restrict__ dinv,
                                                 const unsigned short* __restrict__ Yt,
                                                 const float* __restrict__ bias,
                                                 void* __restrict__ outp) {
    constexpr int BM = 128;
    constexpr int NF = BN / 32;           // per-wave n-frags (2x2 wave grid)
    const int lid = blockIdx.x;
    const int g = (lid & 7) * 64 + (lid >> 3);   // bijective XCD swizzle: 4 batches/XCD
    const int b = g >> 4;
    const int row0 = (g & 15) * BM;
    const int tid = threadIdx.x;
    const int lane = tid & 63, wv = tid >> 6;
    const int wm = wv >> 1, wn = wv & 1;
    const int l15 = lane & 15, lg = lane >> 4;

    __shared__ alignas(16) unsigned short Ys[2][BN * 64];  // double-buffered swizzled tiles
    __shared__ alignas(128) unsigned short LUT4[64];       // 16 entries x 4 bf16 {0,1}
    __shared__ float sdinv[BM];
    if (tid < 16) {
        ushort4 e;
        e.x = (tid & 1) ? 0x3F80 : 0; e.y = (tid & 2) ? 0x3F80 : 0;
        e.z = (tid & 4) ? 0x3F80 : 0; e.w = (tid & 8) ? 0x3F80 : 0;
        *(ushort4*)&LUT4[tid * 4] = e;
    }
    if (tid < BM) sdinv[tid] = dinv[b * NPTS + row0 + tid];

    f32x4 acc[4][NF];
    #pragma unroll
    for (int mf = 0; mf < 4; ++mf)
        #pragma unroll
        for (int nf = 0; nf < NF; ++nf)
            acc[mf][nf] = (f32x4){0.f, 0.f, 0.f, 0.f};

    const int ktd = (row0 >> 6) + wm;     // K-tile containing this wave's diagonal
    const int cst = lane >> 3;            // staging sub-row
    const int sst = lane & 7;             // staging stored slot
    // transposed-mask base: word-plane stride NPTS, row offset per lane
    const uint32_t* mtb = maskT + (size_t)b * 64 * NPTS + row0 + wm * 64 + l15;

    auto stage = [&](int buf, int kt) {
        #pragma unroll
        for (int q = 0; q < BN / 32; ++q) {
            int j = wv * (BN / 32) + q;
            int c = j * 8 + cst;
            int slot = sst ^ (c & 7);
            const unsigned short* gsrc = Yt + (size_t)c * NFLAT + b * NPTS + kt * 64 + slot * 8;
            gl_lds16(gsrc, (char*)&Ys[buf][0] + j * 1024);
        }
    };
    auto mload = [&](uint32_t (&M)[8], int kt) {
        #pragma unroll
        for (int mf = 0; mf < 4; ++mf)
            #pragma unroll
            for (int q = 0; q < 2; ++q)
                M[mf * 2 + q] = mtb[(size_t)(kt * 2 + q) * NPTS + mf * 16];
    };
    auto body = [&](const uint32_t (&M)[8], int buf, int kt) {
        const char* ybase = (const char*)&Ys[buf][0];
        #pragma unroll
        for (int kk2 = 0; kk2 < 2; ++kk2) {
            bf16x8 af[4];
            #pragma unroll
            for (int mf = 0; mf < 4; ++mf) {
                uint32_t by = (M[mf * 2 + kk2] >> (lg * 8)) & 0xffu;
                bf16x4 lo = *(const bf16x4*)&LUT4[(by & 15u) * 4];
                bf16x4 hi = *(const bf16x4*)&LUT4[(by >> 4) * 4];
                af[mf] = __builtin_shufflevector(lo, hi, 0, 1, 2, 3, 4, 5, 6, 7);
            }
            if (kt == ktd) {   // diag weight 2 (self-loop doubling)
                #pragma unroll
                for (int mf = 0; mf < 4; ++mf) {
                    int e = mf * 16 + l15 - kk2 * 32 - lg * 8;
                    #pragma unroll
                    for (int e2 = 0; e2 < 8; ++e2)
                        if (e2 == e) af[mf][e2] = (short)0x4000;
                }
            }
            __builtin_amdgcn_s_setprio(1);
            #pragma unroll
            for (int nf = 0; nf < NF; ++nf) {
                int c = wn * (BN / 2) + nf * 16 + l15;
                int slot = ((kk2 << 2) + lg) ^ (c & 7);
                bf16x8 bf = *(const bf16x8*)(ybase + c * 128 + slot * 16);
                #pragma unroll
                for (int mf = 0; mf < 4; ++mf)
                    acc[mf][nf] = __builtin_amdgcn_mfma_f32_16x16x32_bf16(af[mf], bf, acc[mf][nf], 0, 0, 0);
            }
            __builtin_amdgcn_s_setprio(0);
        }
    };

    uint32_t mA[8], mB[8];
    stage(0, 0); mload(mA, 0);
    __syncthreads();                       // drains prologue stage, publishes LUT/sdinv

    for (int kt = 0; kt < NPTS / 64; kt += 2) {
        stage(1, kt + 1); mload(mB, kt + 1);    // issue next tile before computing current
        body(mA, 0, kt);
        __syncthreads();                        // implicit vmcnt(0): stage(kt+1) published
        if (kt + 2 < NPTS / 64) { stage(0, kt + 2); mload(mA, kt + 2); }
        body(mB, 1, kt + 1);
        __syncthreads();
    }

    // ---- epilogue ----
    #pragma unroll
    for (int mf = 0; mf < 4; ++mf) {
        #pragma unroll
        for (int nf = 0; nf < NF; ++nf) {
            const int gc = wn * (BN / 2) + nf * 16 + l15;
            const float bb = bias[gc];
            #pragma unroll
            for (int r = 0; r < 4; ++r) {
                const int lr = wm * 64 + mf * 16 + lg * 4 + r;
                float vv = sdinv[lr] * acc[mf][nf][r] + bb;
                if (RELU) vv = fmaxf(vv, 0.f);
                size_t o = ((size_t)(b * NPTS + row0 + lr)) * BN + gc;
                if (F32OUT) ((float*)outp)[o] = vv;
                else        ((unsigned short*)outp)[o] = f2b(vv);
            }
        }
    }
}

extern "C" void kernel_launch(void* const* d_in, const int* in_sizes, int n_in,
                              void* d_out, int out_size, void* d_ws, size_t ws_size,
                              hipStream_t stream) {
    const float* pts = (const float*)d_in[0];
    const float* W1  = (const float*)d_in[1];
    const float* b1  = (const float*)d_in[2];
    const float* W2  = (const float*)d_in[3];
    const float* b2  = (const float*)d_in[4];
    const float* W3  = (const float*)d_in[5];
    const float* b3  = (const float*)d_in[6];

    char* ws = (char*)d_ws;
    float*          dinv  = (float*)(ws + OFF_DINV);
    uint32_t*       maskT = (uint32_t*)(ws + OFF_MASK);
    unsigned short* Yt    = (unsigned short*)(ws + OFF_YT);
    unsigned short* H     = (unsigned short*)(ws + OFF_H);
    unsigned short* Wb    = (unsigned short*)(ws + OFF_WB);
    float* out = (float*)d_out;

    k_cvtW<<<dim3(128), dim3(256), 0, stream>>>(W2, W3, Wb);
    k_mask<<<dim3(NPTS / MROWS, BATCH), dim3(256), 0, stream>>>(pts, dinv, maskT);
    k_layer1<<<dim3(NPTS / MROWS, BATCH), dim3(256), 0, stream>>>(pts, W1, b1, dinv, maskT, H);
    k_hwT<128, 64><<<dim3(NFLAT / 256, 1), dim3(256), 0, stream>>>(H, Wb, dinv, Yt);
    k_gcnP<128, true, false><<<dim3(512), dim3(256), 0, stream>>>(maskT, dinv, Yt, b2, H);
    k_hwT<256, 128><<<dim3(NFLAT / 256, 2), dim3(256), 0, stream>>>(H, Wb + 64 * 128, dinv, Yt);
    k_gcnP<256, false, true><<<dim3(512), dim3(256), 0, stream>>>(maskT, dinv, Yt, b3, out);
}

// Round 8
// 186.953 us; speedup vs baseline: 2.0442x; 1.2469x over previous
//
#include <hip/hip_runtime.h>
#include <hip/hip_bf16.h>
#include <cstdint>
#include <cstddef>

#define BATCH 32
#define NPTS  2048
#define NFLAT (BATCH * NPTS)   // 65536
#define MROWS 32               // rows per block in mask/layer1 (8 per wave)

typedef __attribute__((ext_vector_type(8))) short bf16x8;   // 8 bf16 (4 VGPRs)
typedef __attribute__((ext_vector_type(4))) short bf16x4;   // 4 bf16 (2 VGPRs)
typedef __attribute__((ext_vector_type(4))) float f32x4;    // C/D frag

__device__ inline unsigned short f2b(float v) {
    __hip_bfloat16 h = __float2bfloat16(v);
    return __builtin_bit_cast(unsigned short, h);
}

__device__ inline void gl_lds16(const void* g, void* l) {
    __builtin_amdgcn_global_load_lds(
        (const __attribute__((address_space(1))) unsigned int*)g,
        (__attribute__((address_space(3))) unsigned int*)l, 16, 0, 0);
}

// ---------------- ws layout (bytes) ----------------
// dinv  : f32  [65536]          @ 0
// maskT : u32  [b][64][2048]    @ 262144    (16 MB)  TRANSPOSED: word-plane major
// Yt    : bf16 [256][65536]     @ 17039360  (32 MB)  transposed dinv-scaled H@W
// H     : bf16 [65536*128max]   @ 50593792  (16 MB)
// Wb    : bf16 [8192+32768]     @ 67371008
#define OFF_DINV 0
#define OFF_MASK 262144
#define OFF_YT   17039360
#define OFF_H    50593792
#define OFF_WB   67371008

// ---------------- convert W2/W3 to bf16 ----------------
__global__ __launch_bounds__(256) void k_cvtW(const float* __restrict__ W2,
                                              const float* __restrict__ W3,
                                              unsigned short* __restrict__ Wb) {
    int i = blockIdx.x * 256 + threadIdx.x;
    if (i < 64 * 128)  Wb[i] = f2b(W2[i]);
    if (i < 128 * 256) Wb[64 * 128 + i] = f2b(W3[i]);
}

// ---------------- adjacency bitmask (transposed layout) + dinv ----------------
__global__ __launch_bounds__(256) void k_mask(const float* __restrict__ pts,
                                              float* __restrict__ dinv,
                                              uint32_t* __restrict__ maskT) {
    const int b = blockIdx.y;
    const int row0 = blockIdx.x * MROWS;
    const int tid = threadIdx.x, lane = tid & 63, wv = tid >> 6;
    __shared__ float px[2112], py[2112];
    __shared__ uint32_t tb[64][MROWS + 1];
    const float2* P = (const float2*)(pts + (size_t)b * NPTS * 2);
    for (int j = tid; j < NPTS; j += 256) {
        float2 p = P[j];
        px[j + (j >> 5)] = p.x; py[j + (j >> 5)] = p.y;
    }
    __syncthreads();
    const int base = 33 * lane;
    for (int rr = 0; rr < MROWS / 4; ++rr) {
        const int il = wv * (MROWS / 4) + rr;
        const int i = row0 + il;
        const float xi = px[i + (i >> 5)], yi = py[i + (i >> 5)];
        uint32_t bits = 0;
        #pragma unroll
        for (int t = 0; t < 32; ++t) {
            float dx = xi - px[base + t], dy = yi - py[base + t];
            bits |= (dx * dx + dy * dy < 1.0f) ? (1u << t) : 0u;
        }
        tb[lane][il] = bits;
        int cnt = __popc(bits);
        #pragma unroll
        for (int off = 32; off; off >>= 1) cnt += __shfl_xor(cnt, off);
        if (lane == 0) dinv[b * NPTS + i] = rsqrtf((float)(cnt + 1));
    }
    __syncthreads();
    const int w = tid >> 2, il0 = (tid & 3) * 8;
    uint32_t* dst = maskT + ((size_t)b * 64 + w) * NPTS + row0 + il0;
    #pragma unroll
    for (int e = 0; e < 8; ++e) dst[e] = tb[w][il0 + e];
}

// ---------------- layer 1 via (An@p)@W1, wave-per-row ----------------
__global__ __launch_bounds__(256) void k_layer1(const float* __restrict__ pts,
                                                const float* __restrict__ W1,
                                                const float* __restrict__ b1,
                                                const float* __restrict__ dinv,
                                                const uint32_t* __restrict__ maskT,
                                                unsigned short* __restrict__ H) {
    const int b = blockIdx.y;
    const int row0 = blockIdx.x * MROWS;
    const int tid = threadIdx.x, lane = tid & 63, wv = tid >> 6;
    __shared__ float u[2112], v[2112];
    const float* dv = dinv + (size_t)b * NPTS;
    const float2* P = (const float2*)(pts + (size_t)b * NPTS * 2);
    for (int j = tid; j < NPTS; j += 256) {
        float d = dv[j]; float2 p = P[j];
        u[j + (j >> 5)] = d * p.x; v[j + (j >> 5)] = d * p.y;
    }
    __syncthreads();
    const float w1x = W1[lane], w1y = W1[64 + lane], bb = b1[lane];
    const int base = 33 * lane;
    const uint32_t* mplane = maskT + ((size_t)b * 64 + lane) * NPTS;
    for (int rr = 0; rr < MROWS / 4; ++rr) {
        const int i = row0 + wv * (MROWS / 4) + rr;
        const uint32_t wreg = mplane[i];
        float sx = 0.f, sy = 0.f;
        #pragma unroll
        for (int t = 0; t < 32; ++t) {
            uint32_t m = 0u - ((wreg >> t) & 1u);
            sx += __uint_as_float(__float_as_uint(u[base + t]) & m);
            sy += __uint_as_float(__float_as_uint(v[base + t]) & m);
        }
        #pragma unroll
        for (int off = 32; off; off >>= 1) {
            sx += __shfl_xor(sx, off);
            sy += __shfl_xor(sy, off);
        }
        sx += u[i + (i >> 5)]; sy += v[i + (i >> 5)];   // extra self-loop (diag weight 2)
        const float di = dv[i];
        float val = di * (sx * w1x + sy * w1y) + bb;
        H[((size_t)b * NPTS + i) * 64 + lane] = f2b(fmaxf(val, 0.f));
    }
}

// ---------------- Yt = dinv_i * (H @ W)^T   (computed as W^T @ H^T) ----------------
template<int CW, int KT>
__global__ __launch_bounds__(256, 2) void k_hwT(const unsigned short* __restrict__ H,
                                                const unsigned short* __restrict__ Wg,
                                                const float* __restrict__ dinv,
                                                unsigned short* __restrict__ Yt) {
    constexpr int BI = 256, BC = 128;
    const int i0 = blockIdx.x * BI;
    const int c0 = blockIdx.y * BC;
    const int tid = threadIdx.x, lane = tid & 63, wv = tid >> 6;
    const int l15 = lane & 15, lg = lane >> 4;

    __shared__ unsigned short Wt[BC][KT + 8];
    for (int idx = tid; idx < BC * KT; idx += 256) {
        int c = idx & (BC - 1), k = idx >> 7;
        Wt[c][k] = Wg[(size_t)k * CW + c0 + c];
    }
    __syncthreads();

    const int iw0 = i0 + wv * 64;
    bf16x8 hb[4][KT / 32];
    #pragma unroll
    for (int if_ = 0; if_ < 4; ++if_) {
        const unsigned short* hrow = H + (size_t)(iw0 + if_ * 16 + l15) * KT;
        #pragma unroll
        for (int kq = 0; kq < KT / 32; ++kq)
            hb[if_][kq] = *(const bf16x8*)(hrow + kq * 32 + lg * 8);
    }

    f32x4 acc[8][4];
    #pragma unroll
    for (int cf = 0; cf < 8; ++cf)
        #pragma unroll
        for (int if_ = 0; if_ < 4; ++if_)
            acc[cf][if_] = (f32x4){0.f, 0.f, 0.f, 0.f};

    #pragma unroll
    for (int kq = 0; kq < KT / 32; ++kq)
        #pragma unroll
        for (int cf = 0; cf < 8; ++cf) {
            bf16x8 wa = *(const bf16x8*)&Wt[cf * 16 + l15][kq * 32 + lg * 8];
            #pragma unroll
            for (int if_ = 0; if_ < 4; ++if_)
                acc[cf][if_] = __builtin_amdgcn_mfma_f32_16x16x32_bf16(wa, hb[if_][kq], acc[cf][if_], 0, 0, 0);
        }

    float dv[4];
    #pragma unroll
    for (int if_ = 0; if_ < 4; ++if_) dv[if_] = dinv[iw0 + if_ * 16 + l15];
    #pragma unroll
    for (int cf = 0; cf < 8; ++cf)
        #pragma unroll
        for (int if_ = 0; if_ < 4; ++if_) {
            const int ig = iw0 + if_ * 16 + l15;
            #pragma unroll
            for (int r = 0; r < 4; ++r) {
                const int cg = c0 + cf * 16 + lg * 4 + r;
                Yt[(size_t)cg * NFLAT + ig] = f2b(dv[if_] * acc[cf][if_][r]);
            }
        }
}

// ---------------- masked GCN GEMM (round-3 schedule + nibble LUT + plane-major Ms) ----
// Per K-tile: stage Ys via global_load_lds -> vmcnt(0) -> sync -> compute -> sync.
// A expanded from Ms bitmask via 128B nibble-LUT (one 4B word per bank: conflict-free).
template<int BN, bool RELU, bool F32OUT>
__global__ __launch_bounds__(256, 2) void k_gcnM(const uint32_t* __restrict__ maskT,
                                                 const float* __restrict__ dinv,
                                                 const unsigned short* __restrict__ Yt,
                                                 const float* __restrict__ bias,
                                                 void* __restrict__ outp) {
    constexpr int BM = 128;
    constexpr int NF = BN / 32;           // per-wave n-frags (2x2 wave grid)
    const int lid = blockIdx.x;
    const int g = (lid & 7) * 64 + (lid >> 3);   // bijective XCD swizzle: 4 batches/XCD
    const int b = g >> 4;
    const int row0 = (g & 15) * BM;
    const int tid = threadIdx.x;
    const int lane = tid & 63, wv = tid >> 6;
    const int wm = wv >> 1, wn = wv & 1;
    const int l15 = lane & 15, lg = lane >> 4;

    __shared__ alignas(16) unsigned short Ys[BN * 64];     // swizzled [c][64] tile
    __shared__ uint32_t Ms[64][BM];                        // plane-major mask slice
    __shared__ alignas(128) unsigned short LUT4[64];       // 16 x 4 bf16 {0,1}
    __shared__ float sdinv[BM];

    if (tid < 16) {
        ushort4 e;
        e.x = (tid & 1) ? 0x3F80 : 0; e.y = (tid & 2) ? 0x3F80 : 0;
        e.z = (tid & 4) ? 0x3F80 : 0; e.w = (tid & 8) ? 0x3F80 : 0;
        *(ushort4*)&LUT4[tid * 4] = e;
    }
    if (tid < BM) sdinv[tid] = dinv[b * NPTS + row0 + tid];
    {   // stage mask slice: 64 planes x 128 rows, coalesced uint4
        const uint32_t* msrc = maskT + (size_t)b * 64 * NPTS + row0;
        #pragma unroll
        for (int k = 0; k < 8; ++k) {
            int idx = tid + k * 256;
            int w = idx >> 5, c4 = idx & 31;
            *(uint4*)&Ms[w][c4 * 4] = *(const uint4*)(msrc + (size_t)w * NPTS + c4 * 4);
        }
    }

    f32x4 acc[4][NF];
    #pragma unroll
    for (int mf = 0; mf < 4; ++mf)
        #pragma unroll
        for (int nf = 0; nf < NF; ++nf)
            acc[mf][nf] = (f32x4){0.f, 0.f, 0.f, 0.f};

    const int ktd = (row0 >> 6) + wm;     // K-tile containing this wave's diagonal
    const int cst = lane >> 3;            // staging sub-row
    const int sst = lane & 7;             // staging stored slot
    const int rr = wm * 64 + l15;         // this lane's Ms row base

    for (int kt = 0; kt < NPTS / 64; ++kt) {
        // ---- stage Yt tile: linear LDS dest + inverse-swizzled global source ----
        #pragma unroll
        for (int q = 0; q < BN / 32; ++q) {
            int j = wv * (BN / 32) + q;
            int c = j * 8 + cst;
            int slot = sst ^ (c & 7);
            const unsigned short* gsrc = Yt + (size_t)c * NFLAT + b * NPTS + kt * 64 + slot * 8;
            gl_lds16(gsrc, (char*)Ys + j * 1024);
        }
        asm volatile("s_waitcnt vmcnt(0)" ::: "memory");
        __syncthreads();

        #pragma unroll
        for (int kk2 = 0; kk2 < 2; ++kk2) {
            bf16x8 af[4];
            #pragma unroll
            for (int mf = 0; mf < 4; ++mf) {
                uint32_t mw = Ms[kt * 2 + kk2][rr + mf * 16];
                uint32_t by = (mw >> (lg * 8)) & 0xffu;
                bf16x4 lo = *(const bf16x4*)&LUT4[(by & 15u) * 4];
                bf16x4 hi = *(const bf16x4*)&LUT4[(by >> 4) * 4];
                af[mf] = __builtin_shufflevector(lo, hi, 0, 1, 2, 3, 4, 5, 6, 7);
            }
            if (kt == ktd) {   // diag weight 2 (self-loop doubling)
                #pragma unroll
                for (int mf = 0; mf < 4; ++mf) {
                    int e = mf * 16 + l15 - kk2 * 32 - lg * 8;
                    #pragma unroll
                    for (int e2 = 0; e2 < 8; ++e2)
                        if (e2 == e) af[mf][e2] = (short)0x4000;
                }
            }
            #pragma unroll
            for (int nf = 0; nf < NF; ++nf) {
                int c = wn * (BN / 2) + nf * 16 + l15;
                int slot = ((kk2 << 2) + lg) ^ (c & 7);
                bf16x8 bf = *(const bf16x8*)((const char*)Ys + c * 128 + slot * 16);
                #pragma unroll
                for (int mf = 0; mf < 4; ++mf)
                    acc[mf][nf] = __builtin_amdgcn_mfma_f32_16x16x32_bf16(af[mf], bf, acc[mf][nf], 0, 0, 0);
            }
        }
        __syncthreads();
    }

    // ---- epilogue ----
    #pragma unroll
    for (int mf = 0; mf < 4; ++mf) {
        #pragma unroll
        for (int nf = 0; nf < NF; ++nf) {
            const int gc = wn * (BN / 2) + nf * 16 + l15;
            const float bb = bias[gc];
            #pragma unroll
            for (int r = 0; r < 4; ++r) {
                const int lr = wm * 64 + mf * 16 + lg * 4 + r;
                float vv = sdinv[lr] * acc[mf][nf][r] + bb;
                if (RELU) vv = fmaxf(vv, 0.f);
                size_t o = ((size_t)(b * NPTS + row0 + lr)) * BN + gc;
                if (F32OUT) ((float*)outp)[o] = vv;
                else        ((unsigned short*)outp)[o] = f2b(vv);
            }
        }
    }
}

extern "C" void kernel_launch(void* const* d_in, const int* in_sizes, int n_in,
                              void* d_out, int out_size, void* d_ws, size_t ws_size,
                              hipStream_t stream) {
    const float* pts = (const float*)d_in[0];
    const float* W1  = (const float*)d_in[1];
    const float* b1  = (const float*)d_in[2];
    const float* W2  = (const float*)d_in[3];
    const float* b2  = (const float*)d_in[4];
    const float* W3  = (const float*)d_in[5];
    const float* b3  = (const float*)d_in[6];

    char* ws = (char*)d_ws;
    float*          dinv  = (float*)(ws + OFF_DINV);
    uint32_t*       maskT = (uint32_t*)(ws + OFF_MASK);
    unsigned short* Yt    = (unsigned short*)(ws + OFF_YT);
    unsigned short* H     = (unsigned short*)(ws + OFF_H);
    unsigned short* Wb    = (unsigned short*)(ws + OFF_WB);
    float* out = (float*)d_out;

    k_cvtW<<<dim3(128), dim3(256), 0, stream>>>(W2, W3, Wb);
    k_mask<<<dim3(NPTS / MROWS, BATCH), dim3(256), 0, stream>>>(pts, dinv, maskT);
    k_layer1<<<dim3(NPTS / MROWS, BATCH), dim3(256), 0, stream>>>(pts, W1, b1, dinv, maskT, H);
    k_hwT<128, 64><<<dim3(NFLAT / 256, 1), dim3(256), 0, stream>>>(H, Wb, dinv, Yt);
    k_gcnM<128, true, false><<<dim3(512), dim3(256), 0, stream>>>(maskT, dinv, Yt, b2, H);
    k_hwT<256, 128><<<dim3(NFLAT / 256, 2), dim3(256), 0, stream>>>(H, Wb + 64 * 128, dinv, Yt);
    k_gcnM<256, false, true><<<dim3(512), dim3(256), 0, stream>>>(maskT, dinv, Yt, b3, out);
}